// Round 1
// baseline (156.113 us; speedup 1.0000x reference)
//
#include <hip/hip_runtime.h>
#include <hip/hip_bf16.h>
#include <cstdint>

#define N_NODES 50000
#define N_EDGES 800000
#define D_IN 128
#define D_HID 256
#define D_OUT 128

typedef __bf16 bf16;
typedef __bf16 bf16x8 __attribute__((ext_vector_type(8)));
typedef __bf16 bf16x4 __attribute__((ext_vector_type(4)));
typedef float f32x4 __attribute__((ext_vector_type(4)));

// ---------------------------------------------------------------------------
// Kernel 1: xb = bf16(x), transposed bf16 weights. aggb prefill REMOVED —
// the node-centric aggregation kernel now writes every aggb row exactly once
// (including the (1+eps)x term), so prep traffic drops 51.2 -> 38.4 MB.
// grid: 6250 x 256 covers N*D_IN/4 exactly.
// ---------------------------------------------------------------------------
__global__ __launch_bounds__(256) void prep_kernel(
    const float* __restrict__ x,
    const float* __restrict__ w1, const float* __restrict__ w2,
    bf16* __restrict__ xb, bf16* __restrict__ w1t, bf16* __restrict__ w2t) {
  const int i = blockIdx.x * 256 + threadIdx.x;
  float4 v = ((const float4*)x)[i];
  ((bf16x4*)xb)[i] = bf16x4{(bf16)v.x, (bf16)v.y, (bf16)v.z, (bf16)v.w};
  if (i < D_IN * D_HID) {            // 32768
    int k = i >> 8, n = i & 255;     // w1[k][n]
    w1t[n * D_IN + k] = (bf16)w1[i];
  } else if (i < 2 * D_IN * D_HID) { // next 32768
    int j = i - D_IN * D_HID;
    int k = j >> 7, n = j & 127;     // w2[k][n]
    w2t[n * D_HID + k] = (bf16)w2[j];
  }
}

// ---------------------------------------------------------------------------
// Kernel 2: CSR row offsets from the SORTED edge_dst array.
// offs[n] = first edge index with dst >= n; offs[N_NODES] = N_EDGES.
// Each boundary thread fills the gap (a, b]; thread 0 fills [0, dst[0]];
// the last thread fills (dst[E-1], N]. Total stores = N+1.
// ---------------------------------------------------------------------------
__global__ __launch_bounds__(256) void csr_kernel(
    const int* __restrict__ dst, int* __restrict__ offs) {
  const int e = blockIdx.x * 256 + threadIdx.x;
  if (e >= N_EDGES) return;
  const int b = dst[e];
  const int a = (e == 0) ? -1 : dst[e - 1];
  for (int n = a + 1; n <= b; ++n) offs[n] = e;
  if (e == N_EDGES - 1)
    for (int n = b + 1; n <= N_NODES; ++n) offs[n] = N_EDGES;
}

// ---------------------------------------------------------------------------
// Kernel 3: node-centric aggregation — one wave per node, ZERO atomics.
// agg[n] = sum_{e in [offs[n],offs[n+1])} val_e * xb[src_e] + (1+eps)*xb[n].
// Lane owns 2 channels (4B gather per edge). f32 accumulation across the
// node's whole run; one packed bf16x2 store per lane at the end.
// Metadata (src/val) loads are wave-uniform -> scalarized via readfirstlane.
// grid: 12500 x 256 = 50000 waves = N_NODES exactly.
// ---------------------------------------------------------------------------
__global__ __launch_bounds__(256) void node_agg_kernel(
    const bf16* __restrict__ xb, const int* __restrict__ src,
    const float* __restrict__ val, const int* __restrict__ offs,
    const float* __restrict__ eps, bf16* __restrict__ aggb) {
  const int node = __builtin_amdgcn_readfirstlane(
      (blockIdx.x << 2) | (threadIdx.x >> 6));
  const int lane = threadIdx.x & 63;
  const int s = __builtin_amdgcn_readfirstlane(offs[node]);
  const int e = __builtin_amdgcn_readfirstlane(offs[node + 1]);

  float2 acc = make_float2(0.f, 0.f);
  int i = s;
  for (; i + 8 <= e; i += 8) {
    int sv[8]; float vv[8]; int g[8];
    #pragma unroll
    for (int t = 0; t < 8; ++t) { sv[t] = src[i + t]; vv[t] = val[i + t]; }
    #pragma unroll
    for (int t = 0; t < 8; ++t)
      g[t] = *(const int*)&xb[(long)sv[t] * D_IN + lane * 2];
    #pragma unroll
    for (int t = 0; t < 8; ++t) {
      float gx = __uint_as_float((unsigned)g[t] << 16);
      float gy = __uint_as_float((unsigned)g[t] & 0xffff0000u);
      acc.x = fmaf(vv[t], gx, acc.x);
      acc.y = fmaf(vv[t], gy, acc.y);
    }
  }
  for (; i < e; ++i) {
    int sv = src[i]; float vv = val[i];
    int g = *(const int*)&xb[(long)sv * D_IN + lane * 2];
    acc.x = fmaf(vv, __uint_as_float((unsigned)g << 16), acc.x);
    acc.y = fmaf(vv, __uint_as_float((unsigned)g & 0xffff0000u), acc.y);
  }

  const float scale = 1.0f + eps[0];
  int xg = *(const int*)&xb[(long)node * D_IN + lane * 2];
  acc.x = fmaf(scale, __uint_as_float((unsigned)xg << 16), acc.x);
  acc.y = fmaf(scale, __uint_as_float((unsigned)xg & 0xffff0000u), acc.y);

  union { struct { bf16 x, y; } h; int i_; } u;
  u.h.x = (bf16)acc.x; u.h.y = (bf16)acc.y;
  *(int*)&aggb[(long)node * D_IN + lane * 2] = u.i_;
}

// ---------------------------------------------------------------------------
// Kernel 4: FUSED 2-layer MLP. out = relu(A@W1+b1)@W2 + b2, h never leaves
// LDS. Per block: 64 rows. Phase 1: A tile in LDS, W1 fragments in registers
// (loaded directly from global in verified fragment layout: per-lane row =
// l15, k = ks*32+quad*8), wave w computes h cols [w*64,w*64+64). h -> LDS
// bf16. Phase 2: W2 fragments in registers, wave w computes out cols
// [w*32,w*32+32), A-fragments read from Hs. 128 MFMA/wave per block.
// Fragment layouts identical to rounds 1-3 verified kernel:
//   A: a[j]=A[l15][quad*8+j]; B: b[j]=Wt[l15][quad*8+j]; C: row=quad*4+r,col=l15.
// LDS = 17.4KB (As) + 33.8KB (Hs) = 51.2KB -> 3 blocks/CU.
// ---------------------------------------------------------------------------
__global__ __launch_bounds__(256) void mlp_fused(
    const bf16* __restrict__ A, const bf16* __restrict__ W1t,
    const bf16* __restrict__ W2t, const float* __restrict__ b1,
    const float* __restrict__ b2, float* __restrict__ out) {
  constexpr int LDA = 136;  // 272B row stride: 2-way bank aliasing only
  constexpr int LDH = 264;  // 528B row stride: 2-way bank aliasing only
  __shared__ alignas(16) bf16 As[64][LDA];
  __shared__ alignas(16) bf16 Hs[64][LDH];

  const int tid = threadIdx.x;
  const int m0 = blockIdx.x * 64;
  const int wave = tid >> 6;
  const int lane = tid & 63;
  const int l15 = lane & 15;
  const int quad = lane >> 4;

  // Stage A: 64 rows x 128 k, bf16x8 chunks, 4 per thread.
  #pragma unroll
  for (int it = 0; it < 4; ++it) {
    int idx = tid + it * 256;          // 0..1023
    int r = idx >> 4;
    int c8 = (idx & 15) << 3;
    int row = m0 + r; if (row >= N_NODES) row = N_NODES - 1;
    *(bf16x8*)&As[r][c8] = *(const bf16x8*)&A[(long)row * D_IN + c8];
  }

  // W1 fragments: wave covers h cols [wave*64, wave*64+64). 64 VGPRs.
  bf16x8 w1f[4][4];  // [nf][ks]
  #pragma unroll
  for (int nf = 0; nf < 4; ++nf) {
    int n = wave * 64 + nf * 16 + l15;
    #pragma unroll
    for (int ks = 0; ks < 4; ++ks)
      w1f[nf][ks] = *(const bf16x8*)&W1t[(long)n * D_IN + ks * 32 + quad * 8];
  }
  __syncthreads();

  // Phase 1: h[0:64, wave*64 : wave*64+64) = relu(A @ W1 + b1)
  f32x4 acc[4][4] = {};  // [mf][nf]
  #pragma unroll
  for (int ks = 0; ks < 4; ++ks) {
    int kq = ks * 32 + quad * 8;
    bf16x8 a[4];
    #pragma unroll
    for (int mf = 0; mf < 4; ++mf)
      a[mf] = *(const bf16x8*)&As[mf * 16 + l15][kq];
    #pragma unroll
    for (int mf = 0; mf < 4; ++mf)
      #pragma unroll
      for (int nf = 0; nf < 4; ++nf)
        acc[mf][nf] = __builtin_amdgcn_mfma_f32_16x16x32_bf16(
            a[mf], w1f[nf][ks], acc[mf][nf], 0, 0, 0);
  }

  #pragma unroll
  for (int nf = 0; nf < 4; ++nf) {
    int col = wave * 64 + nf * 16 + l15;
    float bv = b1[col];
    #pragma unroll
    for (int mf = 0; mf < 4; ++mf)
      #pragma unroll
      for (int r = 0; r < 4; ++r)
        Hs[mf * 16 + quad * 4 + r][col] = (bf16)fmaxf(acc[mf][nf][r] + bv, 0.f);
  }

  // W2 fragments: wave covers out cols [wave*32, wave*32+32). 64 VGPRs
  // (w1f + phase-1 acc are dead by now).
  bf16x8 w2f[2][8];  // [nf2][ks2]
  #pragma unroll
  for (int nf2 = 0; nf2 < 2; ++nf2) {
    int n = wave * 32 + nf2 * 16 + l15;
    #pragma unroll
    for (int ks2 = 0; ks2 < 8; ++ks2)
      w2f[nf2][ks2] = *(const bf16x8*)&W2t[(long)n * D_HID + ks2 * 32 + quad * 8];
  }
  __syncthreads();

  // Phase 2: out[0:64, wave*32 : wave*32+32) = h @ W2 + b2
  f32x4 acc2[4][2] = {};  // [mf][nf2]
  #pragma unroll
  for (int ks2 = 0; ks2 < 8; ++ks2) {
    int kq = ks2 * 32 + quad * 8;
    bf16x8 ha[4];
    #pragma unroll
    for (int mf = 0; mf < 4; ++mf)
      ha[mf] = *(const bf16x8*)&Hs[mf * 16 + l15][kq];
    #pragma unroll
    for (int mf = 0; mf < 4; ++mf)
      #pragma unroll
      for (int nf2 = 0; nf2 < 2; ++nf2)
        acc2[mf][nf2] = __builtin_amdgcn_mfma_f32_16x16x32_bf16(
            ha[mf], w2f[nf2][ks2], acc2[mf][nf2], 0, 0, 0);
  }

  #pragma unroll
  for (int nf2 = 0; nf2 < 2; ++nf2) {
    int col = wave * 32 + nf2 * 16 + l15;
    float bv = b2[col];
    #pragma unroll
    for (int mf = 0; mf < 4; ++mf)
      #pragma unroll
      for (int r = 0; r < 4; ++r) {
        int row = m0 + mf * 16 + quad * 4 + r;
        if (row < N_NODES)
          out[(long)row * D_OUT + col] = acc2[mf][nf2][r] + bv;
      }
  }
}

// ---------------------------------------------------------------------------
extern "C" void kernel_launch(void* const* d_in, const int* in_sizes, int n_in,
                              void* d_out, int out_size, void* d_ws, size_t ws_size,
                              hipStream_t stream) {
  const float* x    = (const float*)d_in[0];
  const int*   esrc = (const int*)d_in[1];
  const int*   edst = (const int*)d_in[2];
  const float* evl  = (const float*)d_in[3];
  const float* eps  = (const float*)d_in[4];
  const float* w1   = (const float*)d_in[5];
  const float* b1   = (const float*)d_in[6];
  const float* w2   = (const float*)d_in[7];
  const float* b2   = (const float*)d_in[8];
  float* out = (float*)d_out;

  // workspace layout (16B aligned)
  bf16* aggb = (bf16*)d_ws;                          // 12.8 MB
  bf16* xb   = aggb + (size_t)N_NODES * D_IN;        // 12.8 MB
  bf16* w1t  = xb + (size_t)N_NODES * D_IN;          // 64 KB
  bf16* w2t  = w1t + D_IN * D_HID;                   // 64 KB
  int*  offs = (int*)(w2t + D_HID * D_OUT);          // 200 KB

  prep_kernel<<<(N_NODES * D_IN / 4) / 256, 256, 0, stream>>>(
      x, w1, w2, xb, w1t, w2t);
  csr_kernel<<<(N_EDGES + 255) / 256, 256, 0, stream>>>(edst, offs);
  node_agg_kernel<<<(N_NODES + 3) / 4, 256, 0, stream>>>(
      xb, esrc, evl, offs, eps, aggb);
  mlp_fused<<<(N_NODES + 63) / 64, 256, 0, stream>>>(
      aggb, w1t, w2t, b1, b2, out);
}